// Round 19
// baseline (223.234 us; speedup 1.0000x reference)
//
#include <hip/hip_runtime.h>

#define N_NODES 100000
#define N_EDGES 1600000
#define NBUCK 196            // ceil(N / 512)
#define G1B 1563             // gemm1 blocks (64 rows each)
#define GA1 950              // gemm1 blocks in k_p1 (rest in k_p2)
#define FB 391               // F2 blocks (x 4096 edges)
#define FEDGE 4096
#define BCAP 9216            // per-bucket capacity: mean 8192, sigma~90 -> 11 sigma

typedef __attribute__((ext_vector_type(8))) short short8v;   // 8 bf16 (4 VGPRs)
typedef __attribute__((ext_vector_type(4))) float f32x4;

// ---------------- bf16 helpers ----------------
__device__ __forceinline__ unsigned pack_bf16(float a, float b){
  unsigned ua = __float_as_uint(a), ub = __float_as_uint(b);
  ua = ua + 0x7fffu + ((ua >> 16) & 1u);          // RNE
  ub = ub + 0x7fffu + ((ub >> 16) & 1u);
  return (ua >> 16) | (ub & 0xffff0000u);
}
__device__ __forceinline__ unsigned short bf16_of(float a){
  unsigned ua = __float_as_uint(a);
  ua = ua + 0x7fffu + ((ua >> 16) & 1u);
  return (unsigned short)(ua >> 16);
}
__device__ __forceinline__ float bf_lo(unsigned u){ return __uint_as_float(u << 16); }
__device__ __forceinline__ float bf_hi(unsigned u){ return __uint_as_float(u & 0xffff0000u); }

// ---------------- threefry2x32 (JAX partitionable) dropout mask ------------
__device__ __forceinline__ unsigned tf_rotl(unsigned x, int r){ return (x<<r)|(x>>(32-r)); }

__device__ __forceinline__ unsigned dropout_keep(unsigned e){
  unsigned x0 = 0u, x1 = e;
  const unsigned k0 = 0u, k1v = 42u;
  const unsigned k2 = 0x1BD11BDAu ^ k0 ^ k1v;
#define TF_R(r) { x0 += x1; x1 = tf_rotl(x1,(r)); x1 ^= x0; }
  x0 += k0; x1 += k1v;
  TF_R(13) TF_R(15) TF_R(26) TF_R(6)
  x0 += k1v; x1 += k2 + 1u;
  TF_R(17) TF_R(29) TF_R(16) TF_R(24)
  x0 += k2; x1 += k0 + 2u;
  TF_R(13) TF_R(15) TF_R(26) TF_R(6)
  x0 += k0; x1 += k1v + 3u;
  TF_R(17) TF_R(29) TF_R(16) TF_R(24)
  x0 += k1v; x1 += k2 + 4u;
  TF_R(13) TF_R(15) TF_R(26) TF_R(6)
  x0 += k2; x1 += k0 + 5u;
#undef TF_R
  return (x0 ^ x1) >> 31;
}

// ---------------- gemm1 tile (shared by k_p1/k_p2) --------------------------
// h1u[N][128] bf16 = x @ W1; MFMA 16x16x32; no LDS (A inline from x, B from
// L2-resident W1T).
__device__ __forceinline__ void gemm1_block(int gb, int t,
                                            const float* __restrict__ x,
                                            const unsigned short* __restrict__ W1T,
                                            unsigned short* __restrict__ h1u, int N){
  int w = t >> 6, l = t & 63;
  int lo = l & 15, hi = l >> 4;
  int rowA = gb*64 + w*16 + lo;
  int rA = (rowA < N) ? rowA : (N-1);
  const float4* xr = (const float4*)(x + (size_t)rA*128);

  short8v a[4];
  #pragma unroll
  for (int kk = 0; kk < 4; kk++){
    float4 f0 = xr[kk*8 + 2*hi];
    float4 f1 = xr[kk*8 + 2*hi + 1];
    union { short8v v; unsigned u[4]; } A;
    A.u[0] = pack_bf16(f0.x, f0.y);
    A.u[1] = pack_bf16(f0.z, f0.w);
    A.u[2] = pack_bf16(f1.x, f1.y);
    A.u[3] = pack_bf16(f1.z, f1.w);
    a[kk] = A.v;
  }
  int rowC0 = gb*64 + w*16 + hi*4;
  #pragma unroll
  for (int tt = 0; tt < 8; tt++){
    int n0 = tt*16;
    const uint4* brow = (const uint4*)(W1T + (n0 + lo)*128);
    f32x4 acc = {0.f, 0.f, 0.f, 0.f};
    #pragma unroll
    for (int kk = 0; kk < 4; kk++){
      union { short8v v; uint4 q; } B;
      B.q = brow[kk*4 + hi];
      acc = __builtin_amdgcn_mfma_f32_16x16x32_bf16(a[kk], B.v, acc, 0, 0, 0);
    }
    int colC = n0 + lo;
    #pragma unroll
    for (int r = 0; r < 4; r++){
      int rc = rowC0 + r;
      if (rc < N) h1u[(size_t)rc*128 + colC] = bf16_of(acc[r]);
    }
  }
}

// ---------------- k_p0: init roles + F2 bucket-append -----------------------
// blocks 0..64: W1T/W2T48 build (needed only by later dispatches);
// blocks 65..455: F2 with per-wave hist (packed u32 records).
__launch_bounds__(256)
__global__ void k_p0(const float* __restrict__ W1, const float* __restrict__ W2,
                     unsigned short* __restrict__ W1T, unsigned short* __restrict__ W2T48,
                     const int* __restrict__ src, const int* __restrict__ dst,
                     int* __restrict__ bcur2, unsigned* __restrict__ tmp, int E){
  __shared__ int hist[4][200];
  int t = threadIdx.x;
  if (blockIdx.x < 64){
    int idx = blockIdx.x*256 + t;          // 16384 = 128*128
    int k = idx >> 7, n = idx & 127;
    W1T[n*128 + k] = bf16_of(W1[idx]);
    return;
  }
  if (blockIdx.x == 64){
    for (int i = t; i < 48*128; i += 256){
      int c = i >> 7, k = i & 127;
      W2T48[c*128 + k] = (c < 40) ? bf16_of(W2[k*40 + c]) : (unsigned short)0;
    }
    return;
  }
  int fb = blockIdx.x - 65;
  int w = t >> 6, lane = t & 63;
  for (int i = lane; i < NBUCK; i += 64) hist[w][i] = 0;
  __syncthreads();
  int e0 = fb*FEDGE;
  #pragma unroll 4
  for (int j = 0; j < FEDGE/256; j++){
    int e = e0 + t + j*256;
    if (e < E) atomicAdd(&hist[w][dst[e] >> 9], 1);
  }
  __syncthreads();
  if (t < NBUCK){
    int c0 = hist[0][t], c1 = hist[1][t], c2 = hist[2][t], c3 = hist[3][t];
    int tot = c0 + c1 + c2 + c3;
    int base = 0;
    if (tot > 0) base = t*BCAP + atomicAdd(&bcur2[t], tot);
    hist[0][t] = base;
    hist[1][t] = base + c0;
    hist[2][t] = base + c0 + c1;
    hist[3][t] = base + c0 + c1 + c2;
  }
  __syncthreads();
  #pragma unroll 4
  for (int j = 0; j < FEDGE/256; j++){
    int e = e0 + t + j*256;
    if (e < E){
      int d = dst[e], s = src[e];
      int p = atomicAdd(&hist[w][d >> 9], 1);
      tmp[p] = ((unsigned)(d & 511) << 17) | (unsigned)s;
    }
  }
}

// ---------------- k_p1: hist role (256-thr) + gemm1 [0,GA1) -----------------
// hist: per-bucket count + 2-node/thread prefix -> degi/off/dii.
__launch_bounds__(256)
__global__ void k_p1(const float* __restrict__ x, const unsigned short* __restrict__ W1T,
                     unsigned short* __restrict__ h1u,
                     const unsigned* __restrict__ tmp, const int* __restrict__ bcur2,
                     int* __restrict__ degi, int* __restrict__ off,
                     float* __restrict__ dii, int N){
  __shared__ int cur[512];
  __shared__ int wtot[4];
  int t = threadIdx.x;
  if (blockIdx.x < NBUCK){
    int b = blockIdx.x;
    cur[t] = 0; cur[t + 256] = 0;
    __syncthreads();
    int m = bcur2[b];
    int base = b*BCAP;
    int node0 = b << 9;
    for (int i = t; i < m; i += 256)
      atomicAdd(&cur[tmp[base + i] >> 17], 1);
    __syncthreads();
    int c0 = cur[2*t], c1 = cur[2*t + 1];
    int s = c0 + c1;
    int lane = t & 63, w = t >> 6;
    int incl = s;
    for (int d = 1; d < 64; d <<= 1){
      int y = __shfl_up(incl, d);
      if (lane >= d) incl += y;
    }
    if (lane == 63) wtot[w] = incl;
    __syncthreads();
    int wb = 0;
    for (int i = 0; i < w; i++) wb += wtot[i];
    int exclPair = wb + incl - s;
    int n0 = node0 + 2*t, n1 = n0 + 1;
    if (n0 < N){
      degi[n0] = c0;
      off[n0]  = base + exclPair;
      dii[n0]  = rsqrtf((float)(c0 + 1));
    }
    if (n1 < N){
      degi[n1] = c1;
      off[n1]  = base + exclPair + c0;
      dii[n1]  = rsqrtf((float)(c1 + 1));
    }
    return;
  }
  int gb = blockIdx.x - NBUCK;
  if (gb < GA1) gemm1_block(gb, t, x, W1T, h1u, N);
}

// ---------------- k_p2: csort role (256-thr) + gemm1 [GA1,G1B) --------------
// csort: counting sort -> int2 csre (src, w=dii[s]*dii[d]); bucket-local.
__launch_bounds__(256)
__global__ void k_p2(const float* __restrict__ x, const unsigned short* __restrict__ W1T,
                     unsigned short* __restrict__ h1u,
                     const unsigned* __restrict__ tmp, int2* __restrict__ csre,
                     const int* __restrict__ off, const int* __restrict__ bcur2,
                     const float* __restrict__ dii, int N){
  __shared__ int   cur[512];
  __shared__ float dl[512];
  int t = threadIdx.x;
  if (blockIdx.x < NBUCK){
    int b = blockIdx.x;
    int node0 = b << 9;
    for (int i = t; i < 512; i += 256){
      int n = node0 + i;
      cur[i] = (n < N) ? off[n] : 0;
      dl[i]  = (n < N) ? dii[n] : 0.f;
    }
    __syncthreads();
    int m = bcur2[b];
    int base = b*BCAP;
    for (int i = t; i < m; i += 256){
      unsigned e = tmp[base + i];
      int dloc = e >> 17;
      int s = e & 0x1FFFFu;
      float w = dii[s] * dl[dloc];
      int p = atomicAdd(&cur[dloc], 1);
      csre[p] = make_int2(s, __float_as_int(w));
    }
    return;
  }
  int gb = GA1 + (blockIdx.x - NBUCK);
  if (gb < G1B) gemm1_block(gb, t, x, W1T, h1u, N);
}

// ---------------- agg1: Bbg(bf16) = dropout(relu(segsum(h1[src]*w)+b1)) -----
// Proven form: wave per dst; int2 edge records in SGPRs; full-wave 64-lane
// u32 gathers; 8-edge unroll. 71us / FETCH 201MB (at gather floor).
__launch_bounds__(256)
__global__ void k_agg1(const unsigned* __restrict__ h1g, unsigned* __restrict__ Bbg,
                       const int2* __restrict__ csre, const int* __restrict__ off,
                       const int* __restrict__ degi, const float* __restrict__ dii,
                       const float* __restrict__ b1, int N){
  int n = blockIdx.x*4 + (threadIdx.x >> 6);
  int lane = threadIdx.x & 63;
  if (n >= N) return;
  n = __builtin_amdgcn_readfirstlane(n);
  float din = dii[n];
  float s2 = din*din;
  unsigned su = h1g[(size_t)n*64 + lane];
  float a0 = bf_lo(su)*s2, a1 = bf_hi(su)*s2;
  int o = off[n], cnt = degi[n];
  int i = 0;
  for (; i + 8 <= cnt; i += 8){
    int2 e0 = csre[o+i+0], e1 = csre[o+i+1], e2 = csre[o+i+2], e3 = csre[o+i+3];
    int2 e4 = csre[o+i+4], e5 = csre[o+i+5], e6 = csre[o+i+6], e7 = csre[o+i+7];
    unsigned u0 = h1g[(size_t)e0.x*64 + lane];
    unsigned u1 = h1g[(size_t)e1.x*64 + lane];
    unsigned u2 = h1g[(size_t)e2.x*64 + lane];
    unsigned u3 = h1g[(size_t)e3.x*64 + lane];
    unsigned u4 = h1g[(size_t)e4.x*64 + lane];
    unsigned u5 = h1g[(size_t)e5.x*64 + lane];
    unsigned u6 = h1g[(size_t)e6.x*64 + lane];
    unsigned u7 = h1g[(size_t)e7.x*64 + lane];
    float w0 = __int_as_float(e0.y), w1 = __int_as_float(e1.y);
    float w2 = __int_as_float(e2.y), w3 = __int_as_float(e3.y);
    float w4 = __int_as_float(e4.y), w5 = __int_as_float(e5.y);
    float w6 = __int_as_float(e6.y), w7 = __int_as_float(e7.y);
    a0 = fmaf(bf_lo(u0), w0, a0); a1 = fmaf(bf_hi(u0), w0, a1);
    a0 = fmaf(bf_lo(u1), w1, a0); a1 = fmaf(bf_hi(u1), w1, a1);
    a0 = fmaf(bf_lo(u2), w2, a0); a1 = fmaf(bf_hi(u2), w2, a1);
    a0 = fmaf(bf_lo(u3), w3, a0); a1 = fmaf(bf_hi(u3), w3, a1);
    a0 = fmaf(bf_lo(u4), w4, a0); a1 = fmaf(bf_hi(u4), w4, a1);
    a0 = fmaf(bf_lo(u5), w5, a0); a1 = fmaf(bf_hi(u5), w5, a1);
    a0 = fmaf(bf_lo(u6), w6, a0); a1 = fmaf(bf_hi(u6), w6, a1);
    a0 = fmaf(bf_lo(u7), w7, a0); a1 = fmaf(bf_hi(u7), w7, a1);
  }
  for (; i < cnt; ++i){
    int2 e = csre[o+i];
    unsigned u = h1g[(size_t)e.x*64 + lane];
    float w = __int_as_float(e.y);
    a0 = fmaf(bf_lo(u), w, a0); a1 = fmaf(bf_hi(u), w, a1);
  }
  float2 bb = *(const float2*)(b1 + lane*2);
  a0 = fmaxf(a0 + bb.x, 0.f);
  a1 = fmaxf(a1 + bb.y, 0.f);
  unsigned e0i = (unsigned)n*128u + (unsigned)lane*2u;
  a0 = dropout_keep(e0i)      ? a0*2.f : 0.f;
  a1 = dropout_keep(e0i + 1u) ? a1*2.f : 0.f;
  Bbg[(size_t)n*64 + lane] = pack_bf16(a0, a1);
}

// ---------------- GEMM2 (MFMA): h2p[N][64] = B @ W2T48^T --------------------
__launch_bounds__(256)
__global__ void k_gemm2(const unsigned* __restrict__ Bbg, const unsigned short* __restrict__ W2T48,
                        unsigned short* __restrict__ h2p, int N){
  int t = threadIdx.x;
  int w = t >> 6, l = t & 63;
  int lo = l & 15, hi = l >> 4;
  int rowA = blockIdx.x*64 + w*16 + lo;
  int rA = (rowA < N) ? rowA : (N-1);
  const uint4* ar = (const uint4*)(Bbg + (size_t)rA*64);

  short8v a[4];
  #pragma unroll
  for (int kk = 0; kk < 4; kk++){
    union { short8v v; uint4 q; } A;
    A.q = ar[kk*4 + hi];
    a[kk] = A.v;
  }
  int rowC0 = blockIdx.x*64 + w*16 + hi*4;
  #pragma unroll
  for (int tt = 0; tt < 3; tt++){
    int n0 = tt*16;
    const uint4* brow = (const uint4*)(W2T48 + (n0 + lo)*128);
    f32x4 acc = {0.f, 0.f, 0.f, 0.f};
    #pragma unroll
    for (int kk = 0; kk < 4; kk++){
      union { short8v v; uint4 q; } B;
      B.q = brow[kk*4 + hi];
      acc = __builtin_amdgcn_mfma_f32_16x16x32_bf16(a[kk], B.v, acc, 0, 0, 0);
    }
    int colC = n0 + lo;
    #pragma unroll
    for (int r = 0; r < 4; r++){
      int rc = rowC0 + r;
      if (rc < N) h2p[(size_t)rc*64 + colC] = bf16_of(acc[r]);
    }
  }
}

// ---------------- agg2: out = segsum(h2[src]*w) + b2 ------------------------
__launch_bounds__(256)
__global__ void k_agg2(const unsigned* __restrict__ h2p, float* __restrict__ out,
                       const int2* __restrict__ csre, const int* __restrict__ off,
                       const int* __restrict__ degi, const float* __restrict__ dii,
                       const float* __restrict__ b2, int N){
  int n = blockIdx.x*4 + (threadIdx.x >> 6);
  int lane31 = threadIdx.x & 31;
  int lane   = threadIdx.x & 63;
  if (n >= N) return;
  n = __builtin_amdgcn_readfirstlane(n);
  float din = dii[n];
  float sq = din*din;
  unsigned su = h2p[(size_t)n*32 + lane31];
  float a0 = bf_lo(su)*sq, a1 = bf_hi(su)*sq;
  int o = off[n], cnt = degi[n];
  int i = 0;
  for (; i + 8 <= cnt; i += 8){
    int2 e0 = csre[o+i+0], e1 = csre[o+i+1], e2 = csre[o+i+2], e3 = csre[o+i+3];
    int2 e4 = csre[o+i+4], e5 = csre[o+i+5], e6 = csre[o+i+6], e7 = csre[o+i+7];
    unsigned u0 = h2p[(size_t)e0.x*32 + lane31];
    unsigned u1 = h2p[(size_t)e1.x*32 + lane31];
    unsigned u2 = h2p[(size_t)e2.x*32 + lane31];
    unsigned u3 = h2p[(size_t)e3.x*32 + lane31];
    unsigned u4 = h2p[(size_t)e4.x*32 + lane31];
    unsigned u5 = h2p[(size_t)e5.x*32 + lane31];
    unsigned u6 = h2p[(size_t)e6.x*32 + lane31];
    unsigned u7 = h2p[(size_t)e7.x*32 + lane31];
    float w0 = __int_as_float(e0.y), w1 = __int_as_float(e1.y);
    float w2 = __int_as_float(e2.y), w3 = __int_as_float(e3.y);
    float w4 = __int_as_float(e4.y), w5 = __int_as_float(e5.y);
    float w6 = __int_as_float(e6.y), w7 = __int_as_float(e7.y);
    a0 = fmaf(bf_lo(u0), w0, a0); a1 = fmaf(bf_hi(u0), w0, a1);
    a0 = fmaf(bf_lo(u1), w1, a0); a1 = fmaf(bf_hi(u1), w1, a1);
    a0 = fmaf(bf_lo(u2), w2, a0); a1 = fmaf(bf_hi(u2), w2, a1);
    a0 = fmaf(bf_lo(u3), w3, a0); a1 = fmaf(bf_hi(u3), w3, a1);
    a0 = fmaf(bf_lo(u4), w4, a0); a1 = fmaf(bf_hi(u4), w4, a1);
    a0 = fmaf(bf_lo(u5), w5, a0); a1 = fmaf(bf_hi(u5), w5, a1);
    a0 = fmaf(bf_lo(u6), w6, a0); a1 = fmaf(bf_hi(u6), w6, a1);
    a0 = fmaf(bf_lo(u7), w7, a0); a1 = fmaf(bf_hi(u7), w7, a1);
  }
  for (; i < cnt; ++i){
    int2 e = csre[o+i];
    unsigned u = h2p[(size_t)e.x*32 + lane31];
    float w = __int_as_float(e.y);
    a0 = fmaf(bf_lo(u), w, a0); a1 = fmaf(bf_hi(u), w, a1);
  }
  if (lane < 20){
    float2 bb = *(const float2*)(b2 + lane*2);
    a0 += bb.x;
    a1 += bb.y;
    *(float2*)(out + (size_t)n*40 + lane*2) = make_float2(a0, a1);
  }
}

// ---------------- launch ----------------
extern "C" void kernel_launch(void* const* d_in, const int* in_sizes, int n_in,
                              void* d_out, int out_size, void* d_ws, size_t ws_size,
                              hipStream_t stream){
  const float* x  = (const float*)d_in[0];
  const int*   ei = (const int*)  d_in[1];
  const float* W1 = (const float*)d_in[2];
  const float* b1 = (const float*)d_in[3];
  const float* W2 = (const float*)d_in[4];
  const float* b2 = (const float*)d_in[5];
  float* out = (float*)d_out;
  char* ws = (char*)d_ws;
  const int N = N_NODES, E = N_EDGES;
  const int* srcv = ei;
  const int* dstv = ei + E;

  // workspace layout (bytes); total ~83 MB
  int*   bcur2 = (int*)  (ws + 0);          // 196 ints (memset below)
  int*   off   = (int*)  (ws + 8192);       // N ints
  int*   degi  = (int*)  (ws + 417792);     // N ints
  float* dii   = (float*)(ws + 827392);     // N floats
  unsigned short* W1T   = (unsigned short*)(ws + 1236992);  // 32 KB
  unsigned short* W2T48 = (unsigned short*)(ws + 1269760);  // 12 KB
  unsigned* tmp = (unsigned*)(ws + 1290240);  // 196*9216 u32 (7.2 MB) packed edges
  int2*     csre= (int2*)   (ws + 8519680);   // 196*9216 int2 (14.5 MB) (src,w)
  unsigned short* h1u = (unsigned short*)(ws + 23068672);  // [N][128] u16 = 25.6 MB
  unsigned*       h1g = (unsigned*)      (ws + 23068672);  // same memory (u32 pairs)
  unsigned short* h2p = (unsigned short*)(ws + 23068672);  // aliases h1 (dead after agg1)
  unsigned*       Bbg = (unsigned*)      (ws + 56623104);  // [N][64] u32 = 25.6 MB

  hipMemsetAsync(bcur2, 0, 1024, stream);

  // p0: weight-conversion roles + F2 bucket-append (no gemm contention)
  k_p0<<<65 + FB, 256, 0, stream>>>(W1, W2, W1T, W2T48, srcv, dstv, bcur2, tmp, E);
  // p1: hist role (needs F2 done) + gemm1 [0,GA1)  (needs W1T done)
  k_p1<<<NBUCK + GA1, 256, 0, stream>>>(x, W1T, h1u, tmp, bcur2, degi, off, dii, N);
  // p2: csort role (needs hist done) + gemm1 [GA1,G1B)
  k_p2<<<NBUCK + (G1B - GA1), 256, 0, stream>>>(x, W1T, h1u, tmp, csre, off, bcur2, dii, N);

  k_agg1 <<<N/4, 256, 0, stream>>>(h1g, Bbg, csre, off, degi, dii, b1, N);
  k_gemm2<<<(N + 63)/64, 256, 0, stream>>>(Bbg, W2T48, h2p, N);
  k_agg2 <<<N/4, 256, 0, stream>>>((const unsigned*)h2p, out, csre, off, degi, dii, b2, N);
}

// Round 20
// 209.811 us; speedup vs baseline: 1.0640x; 1.0640x over previous
//
#include <hip/hip_runtime.h>

#define N_NODES 100000
#define N_EDGES 1600000
#define NBUCK 196            // ceil(N / 512)
#define G1B 1563             // gemm1 blocks (64 rows each)
#define FB 391               // F2 blocks (x 4096 edges)
#define FEDGE 4096
#define BCAP 9216            // per-bucket capacity: mean 8192, sigma~90 -> 11 sigma

typedef __attribute__((ext_vector_type(8))) short short8v;   // 8 bf16 (4 VGPRs)
typedef __attribute__((ext_vector_type(4))) float f32x4;

// ---------------- bf16 helpers ----------------
__device__ __forceinline__ unsigned pack_bf16(float a, float b){
  unsigned ua = __float_as_uint(a), ub = __float_as_uint(b);
  ua = ua + 0x7fffu + ((ua >> 16) & 1u);          // RNE
  ub = ub + 0x7fffu + ((ub >> 16) & 1u);
  return (ua >> 16) | (ub & 0xffff0000u);
}
__device__ __forceinline__ unsigned short bf16_of(float a){
  unsigned ua = __float_as_uint(a);
  ua = ua + 0x7fffu + ((ua >> 16) & 1u);
  return (unsigned short)(ua >> 16);
}
__device__ __forceinline__ float bf_lo(unsigned u){ return __uint_as_float(u << 16); }
__device__ __forceinline__ float bf_hi(unsigned u){ return __uint_as_float(u & 0xffff0000u); }

// ---------------- threefry2x32 (JAX partitionable) dropout mask ------------
__device__ __forceinline__ unsigned tf_rotl(unsigned x, int r){ return (x<<r)|(x>>(32-r)); }

__device__ __forceinline__ unsigned dropout_keep(unsigned e){
  unsigned x0 = 0u, x1 = e;
  const unsigned k0 = 0u, k1v = 42u;
  const unsigned k2 = 0x1BD11BDAu ^ k0 ^ k1v;
#define TF_R(r) { x0 += x1; x1 = tf_rotl(x1,(r)); x1 ^= x0; }
  x0 += k0; x1 += k1v;
  TF_R(13) TF_R(15) TF_R(26) TF_R(6)
  x0 += k1v; x1 += k2 + 1u;
  TF_R(17) TF_R(29) TF_R(16) TF_R(24)
  x0 += k2; x1 += k0 + 2u;
  TF_R(13) TF_R(15) TF_R(26) TF_R(6)
  x0 += k0; x1 += k1v + 3u;
  TF_R(17) TF_R(29) TF_R(16) TF_R(24)
  x0 += k1v; x1 += k2 + 4u;
  TF_R(13) TF_R(15) TF_R(26) TF_R(6)
  x0 += k2; x1 += k0 + 5u;
#undef TF_R
  return (x0 ^ x1) >> 31;
}

// ---------------- k_init: bcur2=0, W1T(bf16), W2T48(bf16, zero-padded) ------
__global__ void k_init(const float* __restrict__ W1, const float* __restrict__ W2,
                       unsigned short* __restrict__ W1T, unsigned short* __restrict__ W2T48,
                       int* __restrict__ bcur2){
  int b = blockIdx.x, t = threadIdx.x;
  if (b < 64){
    int idx = b*256 + t;           // 16384 = 128*128
    int k = idx >> 7, n = idx & 127;
    W1T[n*128 + k] = bf16_of(W1[idx]);
  } else {
    if (t < NBUCK) bcur2[t] = 0;
    for (int i = t; i < 48*128; i += 256){
      int c = i >> 7, k = i & 127;
      W2T48[c*128 + k] = (c < 40) ? bf16_of(W2[k*40 + c]) : (unsigned short)0;
    }
  }
}

// ---------------- k_B: F2 bucket-append (packed u32) + MFMA gemm1 -----------
// gemm role now stages the 64x128 bf16 C-tile in LDS and stores h1u with
// coalesced uint4 writes (was: 2B scattered stores at 256B stride -> 32
// partial writes per 64B line). [64][136] pad -> 272B row = 17x16B aligned.
__launch_bounds__(256)
__global__ void k_B(const float* __restrict__ x, const unsigned short* __restrict__ W1T,
                    unsigned short* __restrict__ h1u,
                    const int* __restrict__ src, const int* __restrict__ dst,
                    int* __restrict__ bcur2, unsigned* __restrict__ tmp, int N, int E){
  __shared__ int hist[4][200];
  __shared__ unsigned short Cs[64][136];
  int t = threadIdx.x;
  if (blockIdx.x < FB){
    int fb = blockIdx.x;
    int w = t >> 6, lane = t & 63;
    for (int i = lane; i < NBUCK; i += 64) hist[w][i] = 0;
    __syncthreads();
    int e0 = fb*FEDGE;
    #pragma unroll 4
    for (int j = 0; j < FEDGE/256; j++){
      int e = e0 + t + j*256;
      if (e < E) atomicAdd(&hist[w][dst[e] >> 9], 1);
    }
    __syncthreads();
    if (t < NBUCK){
      int c0 = hist[0][t], c1 = hist[1][t], c2 = hist[2][t], c3 = hist[3][t];
      int tot = c0 + c1 + c2 + c3;
      int base = 0;
      if (tot > 0) base = t*BCAP + atomicAdd(&bcur2[t], tot);
      hist[0][t] = base;
      hist[1][t] = base + c0;
      hist[2][t] = base + c0 + c1;
      hist[3][t] = base + c0 + c1 + c2;
    }
    __syncthreads();
    #pragma unroll 4
    for (int j = 0; j < FEDGE/256; j++){
      int e = e0 + t + j*256;
      if (e < E){
        int d = dst[e], s = src[e];
        int p = atomicAdd(&hist[w][d >> 9], 1);
        tmp[p] = ((unsigned)(d & 511) << 17) | (unsigned)s;
      }
    }
    return;
  }
  // ---------- MFMA gemm role ----------
  int gb = blockIdx.x - FB;
  if (gb >= G1B) return;
  int w = t >> 6, l = t & 63;
  int lo = l & 15, hi = l >> 4;
  int rowA = gb*64 + w*16 + lo;
  int rA = (rowA < N) ? rowA : (N-1);
  const float4* xr = (const float4*)(x + (size_t)rA*128);

  short8v a[4];
  #pragma unroll
  for (int kk = 0; kk < 4; kk++){
    float4 f0 = xr[kk*8 + 2*hi];
    float4 f1 = xr[kk*8 + 2*hi + 1];
    union { short8v v; unsigned u[4]; } A;
    A.u[0] = pack_bf16(f0.x, f0.y);
    A.u[1] = pack_bf16(f0.z, f0.w);
    A.u[2] = pack_bf16(f1.x, f1.y);
    A.u[3] = pack_bf16(f1.z, f1.w);
    a[kk] = A.v;
  }
  int rowL0 = w*16 + hi*4;
  #pragma unroll
  for (int tt = 0; tt < 8; tt++){
    int n0 = tt*16;
    const uint4* brow = (const uint4*)(W1T + (n0 + lo)*128);
    f32x4 acc = {0.f, 0.f, 0.f, 0.f};
    #pragma unroll
    for (int kk = 0; kk < 4; kk++){
      union { short8v v; uint4 q; } B;
      B.q = brow[kk*4 + hi];
      acc = __builtin_amdgcn_mfma_f32_16x16x32_bf16(a[kk], B.v, acc, 0, 0, 0);
    }
    #pragma unroll
    for (int r = 0; r < 4; r++)
      Cs[rowL0 + r][n0 + lo] = bf16_of(acc[r]);
  }
  __syncthreads();
  size_t row0 = (size_t)gb*64;
  #pragma unroll
  for (int j = 0; j < 4; j++){
    int idx = t + j*256;           // 1024 uint4 chunks: row = idx/16, pos = idx%16
    int row = idx >> 4, p = idx & 15;
    size_t gr = row0 + row;
    if (gr < (size_t)N)
      *(uint4*)(h1u + gr*128 + p*8) = *(const uint4*)(&Cs[row][p*8]);
  }
}

// ---------------- k_hist: per-bucket hist + prefix -> degi/off/dii ----------
__launch_bounds__(1024)
__global__ void k_hist(const unsigned* __restrict__ tmp, const int* __restrict__ bcur2,
                       int* __restrict__ degi, int* __restrict__ off,
                       float* __restrict__ dii, int N){
  __shared__ int cur[512];
  __shared__ int wtot[8];
  int b = blockIdx.x, t = threadIdx.x;
  if (t < 512) cur[t] = 0;
  __syncthreads();
  int m = bcur2[b];
  int base = b*BCAP;
  int node0 = b << 9;
  for (int i = t; i < m; i += 1024)
    atomicAdd(&cur[tmp[base + i] >> 17], 1);
  __syncthreads();
  if (t < 512){
    int v = cur[t];
    int lane = t & 63, w = t >> 6;
    int incl = v;
    for (int d = 1; d < 64; d <<= 1){
      int y = __shfl_up(incl, d);
      if (lane >= d) incl += y;
    }
    if (lane == 63) wtot[w] = incl;
    __syncthreads();
    int wb = 0;
    for (int i = 0; i < w; i++) wb += wtot[i];
    int excl = wb + incl - v;
    int n = node0 + t;
    if (n < N){
      degi[n] = v;
      off[n]  = base + excl;
      dii[n]  = rsqrtf((float)(v + 1));
    }
  }
}

// ---------------- k_csort: counting sort -> int2 csre (src, w) --------------
__launch_bounds__(1024)
__global__ void k_csort(const unsigned* __restrict__ tmp, int2* __restrict__ csre,
                        const int* __restrict__ off, const int* __restrict__ bcur2,
                        const float* __restrict__ dii, int N){
  __shared__ int   cur[512];
  __shared__ float dl[512];
  int b = blockIdx.x, t = threadIdx.x;
  int node0 = b << 9;
  if (t < 512){
    int n = node0 + t;
    cur[t] = (n < N) ? off[n] : 0;
    dl[t]  = (n < N) ? dii[n] : 0.f;
  }
  __syncthreads();
  int m = bcur2[b];
  int base = b*BCAP;
  for (int i = t; i < m; i += 1024){
    unsigned e = tmp[base + i];
    int dloc = e >> 17;
    int s = e & 0x1FFFFu;
    float w = dii[s] * dl[dloc];
    int p = atomicAdd(&cur[dloc], 1);
    csre[p] = make_int2(s, __float_as_int(w));
  }
}

// ---------------- agg1: Bbg(bf16) = dropout(relu(segsum(h1[src]*w)+b1)) -----
// Proven form: wave per dst; int2 edge records in SGPRs; full-wave 64-lane
// u32 gathers; 8-edge unroll. 71us / FETCH 201MB (at gather floor).
__launch_bounds__(256)
__global__ void k_agg1(const unsigned* __restrict__ h1g, unsigned* __restrict__ Bbg,
                       const int2* __restrict__ csre, const int* __restrict__ off,
                       const int* __restrict__ degi, const float* __restrict__ dii,
                       const float* __restrict__ b1, int N){
  int n = blockIdx.x*4 + (threadIdx.x >> 6);
  int lane = threadIdx.x & 63;
  if (n >= N) return;
  n = __builtin_amdgcn_readfirstlane(n);
  float din = dii[n];
  float s2 = din*din;
  unsigned su = h1g[(size_t)n*64 + lane];
  float a0 = bf_lo(su)*s2, a1 = bf_hi(su)*s2;
  int o = off[n], cnt = degi[n];
  int i = 0;
  for (; i + 8 <= cnt; i += 8){
    int2 e0 = csre[o+i+0], e1 = csre[o+i+1], e2 = csre[o+i+2], e3 = csre[o+i+3];
    int2 e4 = csre[o+i+4], e5 = csre[o+i+5], e6 = csre[o+i+6], e7 = csre[o+i+7];
    unsigned u0 = h1g[(size_t)e0.x*64 + lane];
    unsigned u1 = h1g[(size_t)e1.x*64 + lane];
    unsigned u2 = h1g[(size_t)e2.x*64 + lane];
    unsigned u3 = h1g[(size_t)e3.x*64 + lane];
    unsigned u4 = h1g[(size_t)e4.x*64 + lane];
    unsigned u5 = h1g[(size_t)e5.x*64 + lane];
    unsigned u6 = h1g[(size_t)e6.x*64 + lane];
    unsigned u7 = h1g[(size_t)e7.x*64 + lane];
    float w0 = __int_as_float(e0.y), w1 = __int_as_float(e1.y);
    float w2 = __int_as_float(e2.y), w3 = __int_as_float(e3.y);
    float w4 = __int_as_float(e4.y), w5 = __int_as_float(e5.y);
    float w6 = __int_as_float(e6.y), w7 = __int_as_float(e7.y);
    a0 = fmaf(bf_lo(u0), w0, a0); a1 = fmaf(bf_hi(u0), w0, a1);
    a0 = fmaf(bf_lo(u1), w1, a0); a1 = fmaf(bf_hi(u1), w1, a1);
    a0 = fmaf(bf_lo(u2), w2, a0); a1 = fmaf(bf_hi(u2), w2, a1);
    a0 = fmaf(bf_lo(u3), w3, a0); a1 = fmaf(bf_hi(u3), w3, a1);
    a0 = fmaf(bf_lo(u4), w4, a0); a1 = fmaf(bf_hi(u4), w4, a1);
    a0 = fmaf(bf_lo(u5), w5, a0); a1 = fmaf(bf_hi(u5), w5, a1);
    a0 = fmaf(bf_lo(u6), w6, a0); a1 = fmaf(bf_hi(u6), w6, a1);
    a0 = fmaf(bf_lo(u7), w7, a0); a1 = fmaf(bf_hi(u7), w7, a1);
  }
  for (; i < cnt; ++i){
    int2 e = csre[o+i];
    unsigned u = h1g[(size_t)e.x*64 + lane];
    float w = __int_as_float(e.y);
    a0 = fmaf(bf_lo(u), w, a0); a1 = fmaf(bf_hi(u), w, a1);
  }
  float2 bb = *(const float2*)(b1 + lane*2);
  a0 = fmaxf(a0 + bb.x, 0.f);
  a1 = fmaxf(a1 + bb.y, 0.f);
  unsigned e0i = (unsigned)n*128u + (unsigned)lane*2u;
  a0 = dropout_keep(e0i)      ? a0*2.f : 0.f;
  a1 = dropout_keep(e0i + 1u) ? a1*2.f : 0.f;
  Bbg[(size_t)n*64 + lane] = pack_bf16(a0, a1);
}

// ---------------- GEMM2 (MFMA): h2p[N][64] = B @ W2T48^T --------------------
__launch_bounds__(256)
__global__ void k_gemm2(const unsigned* __restrict__ Bbg, const unsigned short* __restrict__ W2T48,
                        unsigned short* __restrict__ h2p, int N){
  int t = threadIdx.x;
  int w = t >> 6, l = t & 63;
  int lo = l & 15, hi = l >> 4;
  int rowA = blockIdx.x*64 + w*16 + lo;
  int rA = (rowA < N) ? rowA : (N-1);
  const uint4* ar = (const uint4*)(Bbg + (size_t)rA*64);

  short8v a[4];
  #pragma unroll
  for (int kk = 0; kk < 4; kk++){
    union { short8v v; uint4 q; } A;
    A.q = ar[kk*4 + hi];
    a[kk] = A.v;
  }
  int rowC0 = blockIdx.x*64 + w*16 + hi*4;
  #pragma unroll
  for (int tt = 0; tt < 3; tt++){
    int n0 = tt*16;
    const uint4* brow = (const uint4*)(W2T48 + (n0 + lo)*128);
    f32x4 acc = {0.f, 0.f, 0.f, 0.f};
    #pragma unroll
    for (int kk = 0; kk < 4; kk++){
      union { short8v v; uint4 q; } B;
      B.q = brow[kk*4 + hi];
      acc = __builtin_amdgcn_mfma_f32_16x16x32_bf16(a[kk], B.v, acc, 0, 0, 0);
    }
    int colC = n0 + lo;
    #pragma unroll
    for (int r = 0; r < 4; r++){
      int rc = rowC0 + r;
      if (rc < N) h2p[(size_t)rc*64 + colC] = bf16_of(acc[r]);
    }
  }
}

// ---------------- agg2: out = segsum(h2[src]*w) + b2 ------------------------
__launch_bounds__(256)
__global__ void k_agg2(const unsigned* __restrict__ h2p, float* __restrict__ out,
                       const int2* __restrict__ csre, const int* __restrict__ off,
                       const int* __restrict__ degi, const float* __restrict__ dii,
                       const float* __restrict__ b2, int N){
  int n = blockIdx.x*4 + (threadIdx.x >> 6);
  int lane31 = threadIdx.x & 31;
  int lane   = threadIdx.x & 63;
  if (n >= N) return;
  n = __builtin_amdgcn_readfirstlane(n);
  float din = dii[n];
  float sq = din*din;
  unsigned su = h2p[(size_t)n*32 + lane31];
  float a0 = bf_lo(su)*sq, a1 = bf_hi(su)*sq;
  int o = off[n], cnt = degi[n];
  int i = 0;
  for (; i + 8 <= cnt; i += 8){
    int2 e0 = csre[o+i+0], e1 = csre[o+i+1], e2 = csre[o+i+2], e3 = csre[o+i+3];
    int2 e4 = csre[o+i+4], e5 = csre[o+i+5], e6 = csre[o+i+6], e7 = csre[o+i+7];
    unsigned u0 = h2p[(size_t)e0.x*32 + lane31];
    unsigned u1 = h2p[(size_t)e1.x*32 + lane31];
    unsigned u2 = h2p[(size_t)e2.x*32 + lane31];
    unsigned u3 = h2p[(size_t)e3.x*32 + lane31];
    unsigned u4 = h2p[(size_t)e4.x*32 + lane31];
    unsigned u5 = h2p[(size_t)e5.x*32 + lane31];
    unsigned u6 = h2p[(size_t)e6.x*32 + lane31];
    unsigned u7 = h2p[(size_t)e7.x*32 + lane31];
    float w0 = __int_as_float(e0.y), w1 = __int_as_float(e1.y);
    float w2 = __int_as_float(e2.y), w3 = __int_as_float(e3.y);
    float w4 = __int_as_float(e4.y), w5 = __int_as_float(e5.y);
    float w6 = __int_as_float(e6.y), w7 = __int_as_float(e7.y);
    a0 = fmaf(bf_lo(u0), w0, a0); a1 = fmaf(bf_hi(u0), w0, a1);
    a0 = fmaf(bf_lo(u1), w1, a0); a1 = fmaf(bf_hi(u1), w1, a1);
    a0 = fmaf(bf_lo(u2), w2, a0); a1 = fmaf(bf_hi(u2), w2, a1);
    a0 = fmaf(bf_lo(u3), w3, a0); a1 = fmaf(bf_hi(u3), w3, a1);
    a0 = fmaf(bf_lo(u4), w4, a0); a1 = fmaf(bf_hi(u4), w4, a1);
    a0 = fmaf(bf_lo(u5), w5, a0); a1 = fmaf(bf_hi(u5), w5, a1);
    a0 = fmaf(bf_lo(u6), w6, a0); a1 = fmaf(bf_hi(u6), w6, a1);
    a0 = fmaf(bf_lo(u7), w7, a0); a1 = fmaf(bf_hi(u7), w7, a1);
  }
  for (; i < cnt; ++i){
    int2 e = csre[o+i];
    unsigned u = h2p[(size_t)e.x*32 + lane31];
    float w = __int_as_float(e.y);
    a0 = fmaf(bf_lo(u), w, a0); a1 = fmaf(bf_hi(u), w, a1);
  }
  if (lane < 20){
    float2 bb = *(const float2*)(b2 + lane*2);
    a0 += bb.x;
    a1 += bb.y;
    *(float2*)(out + (size_t)n*40 + lane*2) = make_float2(a0, a1);
  }
}

// ---------------- launch ----------------
extern "C" void kernel_launch(void* const* d_in, const int* in_sizes, int n_in,
                              void* d_out, int out_size, void* d_ws, size_t ws_size,
                              hipStream_t stream){
  const float* x  = (const float*)d_in[0];
  const int*   ei = (const int*)  d_in[1];
  const float* W1 = (const float*)d_in[2];
  const float* b1 = (const float*)d_in[3];
  const float* W2 = (const float*)d_in[4];
  const float* b2 = (const float*)d_in[5];
  float* out = (float*)d_out;
  char* ws = (char*)d_ws;
  const int N = N_NODES, E = N_EDGES;
  const int* srcv = ei;
  const int* dstv = ei + E;

  // workspace layout (bytes); total ~83 MB
  int*   bcur2 = (int*)  (ws + 0);          // 196 ints (zeroed in k_init)
  int*   off   = (int*)  (ws + 8192);       // N ints
  int*   degi  = (int*)  (ws + 417792);     // N ints
  float* dii   = (float*)(ws + 827392);     // N floats
  unsigned short* W1T   = (unsigned short*)(ws + 1236992);  // 32 KB
  unsigned short* W2T48 = (unsigned short*)(ws + 1269760);  // 12 KB
  unsigned* tmp = (unsigned*)(ws + 1290240);  // 196*9216 u32 (7.2 MB) packed edges
  int2*     csre= (int2*)   (ws + 8519680);   // 196*9216 int2 (14.5 MB) (src,w)
  unsigned short* h1u = (unsigned short*)(ws + 23068672);  // [N][128] u16 = 25.6 MB
  unsigned*       h1g = (unsigned*)      (ws + 23068672);  // same memory (u32 pairs)
  unsigned short* h2p = (unsigned short*)(ws + 23068672);  // aliases h1 (dead after agg1)
  unsigned*       Bbg = (unsigned*)      (ws + 56623104);  // [N][64] u32 = 25.6 MB

  k_init<<<65, 256, 0, stream>>>(W1, W2, W1T, W2T48, bcur2);
  // F2 bucket-append (per-wave hist) + MFMA gemm1 (LDS-staged coalesced C store)
  k_B<<<FB + G1B, 256, 0, stream>>>(x, W1T, h1u, srcv, dstv, bcur2, tmp, N, E);
  // per-bucket histogram + prefix -> degi/off/dii
  k_hist<<<NBUCK, 1024, 0, stream>>>(tmp, bcur2, degi, off, dii, N);
  // counting sort -> int2 CSR (src, precomputed w)
  k_csort<<<NBUCK, 1024, 0, stream>>>(tmp, csre, off, bcur2, dii, N);

  k_agg1 <<<N/4, 256, 0, stream>>>(h1g, Bbg, csre, off, degi, dii, b1, N);
  k_gemm2<<<(N + 63)/64, 256, 0, stream>>>(Bbg, W2T48, h2p, N);
  k_agg2 <<<N/4, 256, 0, stream>>>((const unsigned*)h2p, out, csre, off, degi, dii, b2, N);
}